// Round 3
// baseline (299.703 us; speedup 1.0000x reference)
//
#include <hip/hip_runtime.h>
#include <hip/hip_bf16.h>

typedef __hip_bfloat16 bf16;

#define R_NUM 40000
#define E_NUM 500000
#define HIST_BLOCKS 1954  // ceil(E/256)
#define XF_BLOCKS 2500    // R/16 (16-row tiles, 4 rows/wave)

// ---------------- new-path ws layout (bytes) ----------------
#define N_CNTS 0
#define N_ROWP 160000
#define N_STB 320000          // E*4 + 256 pad, ends 2,320,256
#define N_XMP0 2320384
#define N_HR0 12560384
#define N_XMP1 33040384
#define N_HR1 43280384
#define NEED2 63760384ull

// ---------------- legacy (PlanD fallback) ws layout ----------------
#define W_P1W 0
#define W_P1B 4096
#define W_APW 4160
#define W_APB 20544
#define W_ABIN 20672
#define W_AVEC 20832
#define W_AW 20960
#define W_AB 29152
#define W_RW 29280
#define W_RB 37472
#define W_END 37600
#define WCONV_BLOCKS 147

#define O_FLAG 0
#define O_WBUF 256
#define O_ROWP 150784
#define O_CNTS 310784
#define O_TMP 470784
#define O_PART 634624
#define O_STB 635136
#define O_BIG 2635392

static __device__ __forceinline__ float b2f(bf16 x) { return __bfloat162float(x); }
static __device__ __forceinline__ float ldv(const float* p, size_t i) { return p[i]; }
static __device__ __forceinline__ float ldv(const bf16* p, size_t i) { return __bfloat162float(p[i]); }
static __device__ __forceinline__ void stv(float* p, size_t i, float v) { p[i] = v; }
static __device__ __forceinline__ void stv(bf16* p, size_t i, float v) { p[i] = __float2bfloat16(v); }

// round-to-nearest-even f32 -> bf16 bits
static __device__ __forceinline__ unsigned int f2bb(float x) {
  union { float f; unsigned int u; } v;
  v.f = x;
  unsigned int r = v.u + 0x7FFFu + ((v.u >> 16) & 1u);
  return r >> 16;
}
static __device__ __forceinline__ unsigned int packxm(float xt, float mt) {
  return f2bb(xt) | (f2bb(mt) << 16);
}

static __device__ __forceinline__ void load_edge(const unsigned int* __restrict__ w, int e,
                                                 int i64, int& h, int& t, int& b) {
  if (i64) {
    h = (int)w[6 * e + 0];
    t = (int)w[6 * e + 2];
    b = (int)w[6 * e + 4];
  } else {
    h = (int)w[3 * e + 0];
    t = (int)w[3 * e + 1];
    b = (int)w[3 * e + 2];
  }
}

// ---------------- detect + zero-init (1 launch) ----------------

__global__ void k_detect_init(const unsigned int* __restrict__ trip_w,
                              const unsigned short* __restrict__ emb_w, int* __restrict__ flag,
                              int* __restrict__ counts, int* __restrict__ stb) {
  int tid = threadIdx.x;
  if (blockIdx.x == 0) {
    if (tid < 64) {
      int lane = tid;
      unsigned int acc = 0;
      for (int i = lane; i < 1024; i += 64) acc |= trip_w[2 * i + 1];
      int votes = 0;
      for (int i = lane; i < 2048; i += 64) {
        unsigned short u = emb_w[2 * i];
        int ex = (u >> 7) & 0xFF;
        if (ex >= 90 && ex <= 130) votes++;
      }
      for (int off = 1; off < 64; off <<= 1) {
        acc |= __shfl_xor(acc, off);
        votes += __shfl_xor(votes, off);
      }
      if (lane == 0) {
        flag[0] = (acc == 0) ? 1 : 0;
        flag[1] = (votes < 1024) ? 1 : 0;
      }
    }
    return;
  }
  int g = (blockIdx.x - 1) * 256 + tid;
  for (int i = g; i < R_NUM; i += 159 * 256) counts[i] = 0;
  if (blockIdx.x == 1 && tid < 64) stb[E_NUM + tid] = 0;
}

// ---------------- shared transform core: 4 fused streams, N rows/wave ----------------

template <typename WT, int N>
static __device__ __forceinline__ void xf4t(const float (*sA)[64], int base, int j, int l,
                                            const WT* __restrict__ apw, const WT* __restrict__ apb,
                                            const WT* __restrict__ aw, const WT* __restrict__ ab,
                                            const WT* __restrict__ rw, const WT* __restrict__ rb,
                                            int r0, unsigned int* __restrict__ XMp,
                                            float2* __restrict__ HR) {
  const WT* pwt = apw + l * 8192;
  const WT* pwb = pwt + 4096;
  const WT* awl = aw + l * 4096;
  const WT* rwl = rw + l * 4096;
  float axt[N] = {};
  float amt[N] = {};
  float axh[N] = {};
  float ars[N] = {};
  for (int i4 = 0; i4 < 64; i4 += 4) {
    float4 ev[N];
#pragma unroll
    for (int n = 0; n < N; n++) ev[n] = *(const float4*)&sA[base + n][i4];
#pragma unroll
    for (int di = 0; di < 4; di++) {
      int i = i4 + di;
      float wt = ldv(pwb, (size_t)i * 64 + j);
      float wm = ldv(awl, (size_t)i * 64 + j);
      float wh = ldv(pwt, (size_t)i * 64 + j);
      float wr = ldv(rwl, (size_t)i * 64 + j);
#pragma unroll
      for (int n = 0; n < N; n++) {
        float e = ((const float*)&ev[n])[di];
        axt[n] = fmaf(e, wt, axt[n]);
        amt[n] = fmaf(e, wm, amt[n]);
        axh[n] = fmaf(e, wh, axh[n]);
        ars[n] = fmaf(e, wr, ars[n]);
      }
    }
  }
  float abj = ldv(ab, (size_t)l * 64 + j);
  float pbj = ldv(apb, (size_t)l * 64 + j);
  float rbj = ldv(rb, (size_t)l * 64 + j);
#pragma unroll
  for (int n = 0; n < N; n++) {
    XMp[(size_t)(r0 + n) * 64 + j] = packxm(axt[n], amt[n] + abj);
    HR[(size_t)(r0 + n) * 64 + j] = make_float2(axh[n] + pbj, fmaxf(ars[n] + rbj, 0.f));
  }
}

// ---------------- kA: emb0/layer-0 transform tiles (first) + hist blocks (1 launch) ----------
// Transform tile = 16 rows, wave-private (4 rows/wave, no cross-wave sync).
// hist writes counts; transform blocks read inputs, write XMp0/HR0 — no cross-block deps.
// The layer-0 emb store is DEAD (edge-l0 consumes XMp/HR only) and is eliminated.

template <typename T>
static __device__ __forceinline__ void kA_xform(const T* __restrict__ A, const T* __restrict__ p1w,
                                                const T* __restrict__ p1b,
                                                const T* __restrict__ apw,
                                                const T* __restrict__ apb, const T* __restrict__ aw,
                                                const T* __restrict__ ab, const T* __restrict__ rw,
                                                const T* __restrict__ rb, int u,
                                                unsigned int* __restrict__ XMp0,
                                                float2* __restrict__ HR0, float (*sA)[64]) {
  int tid = threadIdx.x;
  int j = tid & 63;
  int w = tid >> 6;
  int base = w * 4;
  int r0 = u * 16 + base;
#pragma unroll
  for (int n = 0; n < 4; n++) sA[base + n][j] = ldv(A, (size_t)(r0 + n) * 64 + j);
  // wave-private rows: no __syncthreads needed
  float a[4] = {0.f, 0.f, 0.f, 0.f};
  for (int i4 = 0; i4 < 64; i4 += 4) {
    float4 ev[4];
#pragma unroll
    for (int n = 0; n < 4; n++) ev[n] = *(const float4*)&sA[base + n][i4];
#pragma unroll
    for (int di = 0; di < 4; di++) {
      float wv = ldv(p1w, (size_t)(i4 + di) * 64 + j);
#pragma unroll
      for (int n = 0; n < 4; n++) a[n] = fmaf(((const float*)&ev[n])[di], wv, a[n]);
    }
  }
  float bj = ldv(p1b, j);
#pragma unroll
  for (int n = 0; n < 4; n++) {
    a[n] = fmaxf(a[n] + bj, 0.f);
    sA[base + n][j] = a[n];
  }
  xf4t<T, 4>((const float(*)[64])sA, base, j, 0, apw, apb, aw, ab, rw, rb, r0, XMp0, HR0);
}

__global__ void __launch_bounds__(256, 8) kA(const unsigned int* __restrict__ trip_w,
                                             const int* __restrict__ flag,
                                             const void* __restrict__ A, const void* p1w,
                                             const void* p1b, const void* apw, const void* apb,
                                             const void* aw, const void* ab, const void* rw,
                                             const void* rb, int* __restrict__ counts,
                                             unsigned int* __restrict__ XMp0,
                                             float2* __restrict__ HR0) {
  if (blockIdx.x >= XF_BLOCKS) {
    int e = (blockIdx.x - XF_BLOCKS) * 256 + threadIdx.x;
    if (e < E_NUM) {
      int h = flag[0] ? (int)trip_w[6 * e] : (int)trip_w[3 * e];
      atomicAdd(&counts[h], 1);
    }
    return;
  }
  __shared__ float sA[16][64];
  int u = blockIdx.x;
  if (flag[1])
    kA_xform<float>((const float*)A, (const float*)p1w, (const float*)p1b, (const float*)apw,
                    (const float*)apb, (const float*)aw, (const float*)ab, (const float*)rw,
                    (const float*)rb, u, XMp0, HR0, sA);
  else
    kA_xform<bf16>((const bf16*)A, (const bf16*)p1w, (const bf16*)p1b, (const bf16*)apw,
                   (const bf16*)apb, (const bf16*)aw, (const bf16*)ab, (const bf16*)rw,
                   (const bf16*)rb, u, XMp0, HR0, sA);
}

// ---------------- single-block scan: counts -> exclusive row_ptr (1 launch) ----------------

__global__ void __launch_bounds__(1024) k_scan1(const int* __restrict__ counts,
                                                int* __restrict__ row_ptr) {
  __shared__ int sp[1024];
  int tid = threadIdx.x;
  int base = tid * 40;  // 1000 threads x 40 = 40000
  int local[40];
  int s = 0;
  if (base < R_NUM) {
#pragma unroll
    for (int k = 0; k < 40; k++) {
      int v = counts[base + k];
      local[k] = s;
      s += v;
    }
  }
  sp[tid] = s;
  __syncthreads();
  for (int off = 1; off < 1024; off <<= 1) {
    int t = (tid >= off) ? sp[tid - off] : 0;
    __syncthreads();
    sp[tid] += t;
    __syncthreads();
  }
  int pre = (tid == 0) ? 0 : sp[tid - 1];
  if (base < R_NUM) {
#pragma unroll
    for (int k = 0; k < 40; k++) row_ptr[base + k] = pre + local[k];
  }
}

// scatter bumps row_ptr: afterwards row_ptr[r] == end(r); beg(r) = r ? row_ptr[r-1] : 0
__global__ void k_scatter(const unsigned int* __restrict__ trip_w, const int* __restrict__ flag,
                          int* __restrict__ row_ptr, int* __restrict__ stb) {
  int e = blockIdx.x * 256 + threadIdx.x;
  if (e >= E_NUM) return;
  int h, t, b;
  load_edge(trip_w, e, flag[0], h, t, b);
  int pos = atomicAdd(&row_ptr[h], 1);
  stb[pos] = (t & 0xFFFF) | (b << 16);
}

// ---------------- kB: edge-l0 aggregation + layer-1 transforms (1 launch) ----------------
// Tile = 16 rows: 4 waves x 4 rows, wave-private. Reads XMp0/HR0, writes XMp1/HR1.

template <typename T>
static __device__ __forceinline__ void kB_body(const int* __restrict__ row_ptr,
                                               const int* __restrict__ stb,
                                               const unsigned int* __restrict__ XMp0,
                                               const float2* __restrict__ HR0,
                                               const T* __restrict__ apw, const T* __restrict__ apb,
                                               const T* __restrict__ abin,
                                               const T* __restrict__ avec, const T* __restrict__ aw,
                                               const T* __restrict__ ab, const T* __restrict__ rw,
                                               const T* __restrict__ rb,
                                               unsigned int* __restrict__ XMp1,
                                               float2* __restrict__ HR1, float (*sE)[64],
                                               float* sab) {
  int tid = threadIdx.x;
  int lane = tid & 63;
  int w = tid >> 6;
  int hh = lane >> 3;
  if (tid < 80) {
    float a = ldv(abin, tid);  // l=0
    sab[tid] = (a > 0.f) ? a : 0.2f * a;
  }
  __syncthreads();
  float av = ldv(avec, lane);  // l=0
  int base = w * 4;
  int rbase = blockIdx.x * 16 + base;
#pragma unroll 1
  for (int n = 0; n < 4; n++) {
    int r = rbase + n;
    float2 hr = HR0[(size_t)r * 64 + lane];
    int beg = (r == 0) ? 0 : row_ptr[r - 1];
    int end = row_ptr[r];
    beg = __builtin_amdgcn_readfirstlane(beg);
    end = __builtin_amdgcn_readfirstlane(end);
    float xh = hr.x;
    float num = 0.f, den = 0.f;
    for (int jj = beg; jj < end; jj += 16) {
      int pk[16];
      unsigned int xp[16];
#pragma unroll
      for (int k = 0; k < 16; k++) pk[k] = stb[jj + k];
#pragma unroll
      for (int k = 0; k < 16; k++) xp[k] = XMp0[(size_t)(pk[k] & 0xFFFF) * 64 + lane];
#pragma unroll
      for (int k = 0; k < 16; k++) {
        float xt = __uint_as_float(xp[k] << 16);
        float mt = __uint_as_float(xp[k] & 0xFFFF0000u);
        float z = xh + xt;
        z = (z > 0.f) ? z : 0.2f * z;
        float v = z * av;
        v += __shfl_xor(v, 1);
        v += __shfl_xor(v, 2);
        v += __shfl_xor(v, 4);
        float e = __expf(v + sab[(pk[k] >> 16) * 8 + hh]);
        e = (jj + k < end) ? e : 0.f;
        den += e;
        num = fmaf(mt, e, num);
      }
    }
    sE[base + n][lane] = fmaxf(num / (den + 1e-16f), 0.f) + hr.y;
  }
  // wave-private rows: no __syncthreads needed before xf4t
  xf4t<T, 4>((const float(*)[64])sE, base, lane, 1, apw, apb, aw, ab, rw, rb, rbase, XMp1, HR1);
}

__global__ void __launch_bounds__(256, 8) kB(const int* __restrict__ row_ptr,
                                             const int* __restrict__ stb,
                                             const int* __restrict__ flag,
                                             const unsigned int* __restrict__ XMp0,
                                             const float2* __restrict__ HR0, const void* apw,
                                             const void* apb, const void* abin, const void* avec,
                                             const void* aw, const void* ab, const void* rw,
                                             const void* rb, unsigned int* __restrict__ XMp1,
                                             float2* __restrict__ HR1) {
  __shared__ float sE[16][64];
  __shared__ float sab[80];
  if (flag[1])
    kB_body<float>(row_ptr, stb, XMp0, HR0, (const float*)apw, (const float*)apb,
                   (const float*)abin, (const float*)avec, (const float*)aw, (const float*)ab,
                   (const float*)rw, (const float*)rb, XMp1, HR1, sE, sab);
  else
    kB_body<bf16>(row_ptr, stb, XMp0, HR0, (const bf16*)apw, (const bf16*)apb, (const bf16*)abin,
                  (const bf16*)avec, (const bf16*)aw, (const bf16*)ab, (const bf16*)rw,
                  (const bf16*)rb, XMp1, HR1, sE, sab);
}

// ---------------- kC: edge-l1 aggregation -> final output (1 launch) ----------------

template <typename T>
static __device__ __forceinline__ void kC_body(const int* __restrict__ row_ptr,
                                               const int* __restrict__ stb,
                                               const unsigned int* __restrict__ XMp1,
                                               const float2* __restrict__ HR1,
                                               const T* __restrict__ abin,
                                               const T* __restrict__ avec,
                                               float* __restrict__ out, float* sab) {
  int tid = threadIdx.x;
  int lane = tid & 63;
  int w = tid >> 6;
  int hh = lane >> 3;
  if (tid < 80) {
    float a = ldv(abin, 80 + tid);  // l=1
    sab[tid] = (a > 0.f) ? a : 0.2f * a;
  }
  __syncthreads();
  float av = ldv(avec, 64 + lane);  // l=1

  int r = blockIdx.x * 4 + w;
  float2 hr = HR1[(size_t)r * 64 + lane];
  int beg = (r == 0) ? 0 : row_ptr[r - 1];
  int end = row_ptr[r];
  beg = __builtin_amdgcn_readfirstlane(beg);
  end = __builtin_amdgcn_readfirstlane(end);

  float xh = hr.x;
  float num = 0.f, den = 0.f;
  for (int j = beg; j < end; j += 16) {
    int pk[16];
    unsigned int xp[16];
#pragma unroll
    for (int k = 0; k < 16; k++) pk[k] = stb[j + k];
#pragma unroll
    for (int k = 0; k < 16; k++) xp[k] = XMp1[(size_t)(pk[k] & 0xFFFF) * 64 + lane];
#pragma unroll
    for (int k = 0; k < 16; k++) {
      float xt = __uint_as_float(xp[k] << 16);
      float mt = __uint_as_float(xp[k] & 0xFFFF0000u);
      float z = xh + xt;
      z = (z > 0.f) ? z : 0.2f * z;
      float v = z * av;
      v += __shfl_xor(v, 1);
      v += __shfl_xor(v, 2);
      v += __shfl_xor(v, 4);
      float e = __expf(v + sab[(pk[k] >> 16) * 8 + hh]);
      e = (j + k < end) ? e : 0.f;
      den += e;
      num = fmaf(mt, e, num);
    }
  }
  out[(size_t)r * 64 + lane] = fmaxf(num / (den + 1e-16f), 0.f) + hr.y;
}

__global__ void __launch_bounds__(256, 8) kC(const int* __restrict__ row_ptr,
                                             const int* __restrict__ stb,
                                             const int* __restrict__ flag,
                                             const unsigned int* __restrict__ XMp1,
                                             const float2* __restrict__ HR1, const void* abin,
                                             const void* avec, float* __restrict__ out) {
  __shared__ float sab[80];
  if (flag[1])
    kC_body<float>(row_ptr, stb, XMp1, HR1, (const float*)abin, (const float*)avec, out, sab);
  else
    kC_body<bf16>(row_ptr, stb, XMp1, HR1, (const bf16*)abin, (const bf16*)avec, out, sab);
}

// ==================== legacy fallback (tiny ws): wconv + PlanD ====================

__global__ void k_hist_wconv(const unsigned int* __restrict__ trip_w, const int* __restrict__ flag,
                             int* __restrict__ counts, const void* p1w, const void* p1b,
                             const void* apw, const void* apb, const void* abin, const void* avec,
                             const void* aw, const void* ab, const void* rw, const void* rb,
                             float* __restrict__ wbuf) {
  if (blockIdx.x < WCONV_BLOCKS) {
    int i = blockIdx.x * 256 + threadIdx.x;
    if (i >= W_END) return;
    const void* src;
    int off;
    if (i < W_P1B) { src = p1w; off = i - W_P1W; }
    else if (i < W_APW) { src = p1b; off = i - W_P1B; }
    else if (i < W_APB) { src = apw; off = i - W_APW; }
    else if (i < W_ABIN) { src = apb; off = i - W_APB; }
    else if (i < W_AVEC) { src = abin; off = i - W_ABIN; }
    else if (i < W_AW) { src = avec; off = i - W_AVEC; }
    else if (i < W_AB) { src = aw; off = i - W_AW; }
    else if (i < W_RW) { src = ab; off = i - W_AB; }
    else if (i < W_RB) { src = rw; off = i - W_RW; }
    else { src = rb; off = i - W_RB; }
    wbuf[i] = flag[1] ? ((const float*)src)[off] : b2f(((const bf16*)src)[off]);
    return;
  }
  int e = (blockIdx.x - WCONV_BLOCKS) * 256 + threadIdx.x;
  if (e >= E_NUM) return;
  int h, t, b;
  load_edge(trip_w, e, flag[0], h, t, b);
  atomicAdd(&counts[h], 1);
}

__global__ void k_emb0(const void* __restrict__ A, const int* __restrict__ flag,
                       const float* __restrict__ wbuf, float* __restrict__ emb) {
  int j = threadIdx.x & 63;
  int g = threadIdx.x >> 6;
  int r0 = blockIdx.x * 16 + g * 4;
  int f32 = flag[1];
  __shared__ float sA[16][64];
  for (int k = threadIdx.x; k < 1024; k += 256) {
    int rr = k >> 6, cc = k & 63;
    size_t idx = (size_t)(blockIdx.x * 16 + rr) * 64 + cc;
    sA[rr][cc] = f32 ? ((const float*)A)[idx] : b2f(((const bf16*)A)[idx]);
  }
  __syncthreads();
  const float* W = wbuf + W_P1W;
  float a[4] = {0.f, 0.f, 0.f, 0.f};
  int base = g * 4;
  for (int i = 0; i < 64; i++) {
    float w = W[i * 64 + j];
#pragma unroll
    for (int n = 0; n < 4; n++) a[n] = fmaf(sA[base + n][i], w, a[n]);
  }
  float bj = wbuf[W_P1B + j];
#pragma unroll
  for (int n = 0; n < 4; n++)
    emb[(size_t)(r0 + n) * 64 + j] = fmaxf(a[n] + bj, 0.f);
}

static __device__ __forceinline__ float dotcol(const float* __restrict__ Wm, float val, int lane) {
  float acc = 0.f;
  for (int i = 0; i < 64; i++) acc = fmaf(__shfl(val, i), Wm[i * 64 + lane], acc);
  return acc;
}

template <typename TIN, typename TOUT>
__global__ void k_edge_d(const int* __restrict__ row_ptr, const int* __restrict__ stb,
                         const float* __restrict__ wbuf, int l, const TIN* __restrict__ emb_in,
                         TOUT* __restrict__ emb_out) {
  __shared__ float sab[80];
  int tid = threadIdx.x;
  int lane = tid & 63;
  int w = tid >> 6;
  int r = blockIdx.x * 4 + w;
  int hh = lane >> 3;
  if (tid < 80) {
    float a = wbuf[W_ABIN + l * 80 + tid];
    sab[tid] = (a > 0.f) ? a : 0.2f * a;
  }
  __syncthreads();
  const float* pwt = wbuf + W_APW + l * 8192;
  const float* pwb = pwt + 4096;
  const float* aw = wbuf + W_AW + l * 4096;
  const float* rw = wbuf + W_RW + l * 4096;

  float ev = ldv(emb_in, (size_t)r * 64 + lane);
  float xh = wbuf[W_APB + l * 64 + lane];
  float res = wbuf[W_RB + l * 64 + lane];
  for (int i = 0; i < 64; i++) {
    float e = __shfl(ev, i);
    xh = fmaf(e, pwt[i * 64 + lane], xh);
    res = fmaf(e, rw[i * 64 + lane], res);
  }
  res = fmaxf(res, 0.f);
  float av = wbuf[W_AVEC + l * 64 + lane];
  float abl = wbuf[W_AB + l * 64 + lane];

  int beg = (r == 0) ? 0 : row_ptr[r - 1];
  int end = row_ptr[r];
  float num = 0.f, den = 0.f;
  for (int j = beg; j < end; j++) {
    int p = stb[j];
    int t = p & 0xFFFF;
    float tv = ldv(emb_in, (size_t)t * 64 + lane);
    float z = xh + dotcol(pwb, tv, lane);
    z = (z > 0.f) ? z : 0.2f * z;
    float v = z * av;
    v += __shfl_xor(v, 1);
    v += __shfl_xor(v, 2);
    v += __shfl_xor(v, 4);
    float e = __expf(v + sab[(p >> 16) * 8 + hh]);
    den += e;
    float mt = dotcol(aw, tv, lane) + abl;
    num = fmaf(mt, e, num);
  }
  stv(emb_out, (size_t)r * 64 + lane, fmaxf(num / (den + 1e-16f), 0.f) + res);
}

// ---------------- launch ----------------

extern "C" void kernel_launch(void* const* d_in, const int* in_sizes, int n_in,
                              void* d_out, int out_size, void* d_ws, size_t ws_size,
                              hipStream_t stream) {
  const unsigned int* trip_w = (const unsigned int*)d_in[0];
  const void* rel_emb = d_in[1];
  float* emb = (float*)d_out;
  char* ws = (char*)d_ws;

  if (ws_size >= NEED2) {
    int* counts = (int*)(ws + N_CNTS);
    int* row_ptr = (int*)(ws + N_ROWP);
    int* stb = (int*)(ws + N_STB);
    unsigned int* XMp0 = (unsigned int*)(ws + N_XMP0);
    float2* HR0 = (float2*)(ws + N_HR0);
    unsigned int* XMp1 = (unsigned int*)(ws + N_XMP1);
    float2* HR1 = (float2*)(ws + N_HR1);
    // flag lives in the gap after stb pad (aligned, unused bytes)
    int* flag = (int*)(ws + N_STB + (E_NUM + 64) * 4);

    k_detect_init<<<160, 256, 0, stream>>>(trip_w, (const unsigned short*)rel_emb, flag, counts,
                                           stb);
    kA<<<XF_BLOCKS + HIST_BLOCKS, 256, 0, stream>>>(trip_w, flag, rel_emb, d_in[2], d_in[3],
                                                    d_in[4], d_in[5], d_in[8], d_in[9], d_in[10],
                                                    d_in[11], counts, XMp0, HR0);
    k_scan1<<<1, 1024, 0, stream>>>(counts, row_ptr);
    k_scatter<<<HIST_BLOCKS, 256, 0, stream>>>(trip_w, flag, row_ptr, stb);
    kB<<<XF_BLOCKS, 256, 0, stream>>>(row_ptr, stb, flag, XMp0, HR0, d_in[4], d_in[5], d_in[6],
                                      d_in[7], d_in[8], d_in[9], d_in[10], d_in[11], XMp1, HR1);
    kC<<<R_NUM / 4, 256, 0, stream>>>(row_ptr, stb, flag, XMp1, HR1, d_in[6], d_in[7], emb);
    return;
  }

  // ---- tiny-ws fallback: legacy wconv + PlanD per-edge recompute ----
  {
    int* flag = (int*)(ws + O_FLAG);
    float* wbuf = (float*)(ws + O_WBUF);
    int* row_ptr = (int*)(ws + O_ROWP);
    int* counts = (int*)(ws + O_CNTS);
    int* stb = (int*)(ws + O_STB);
    char* big = ws + O_BIG;

    k_detect_init<<<160, 256, 0, stream>>>(trip_w, (const unsigned short*)rel_emb, flag, counts,
                                           stb);
    k_hist_wconv<<<WCONV_BLOCKS + HIST_BLOCKS, 256, 0, stream>>>(
        trip_w, flag, counts, d_in[2], d_in[3], d_in[4], d_in[5], d_in[6], d_in[7], d_in[8],
        d_in[9], d_in[10], d_in[11], wbuf);
    k_scan1<<<1, 1024, 0, stream>>>(counts, row_ptr);
    k_scatter<<<HIST_BLOCKS, 256, 0, stream>>>(trip_w, flag, row_ptr, stb);
    k_emb0<<<R_NUM / 16, 256, 0, stream>>>(rel_emb, flag, wbuf, emb);
    bf16* embB = (bf16*)big;
    k_edge_d<float, bf16><<<R_NUM / 4, 256, 0, stream>>>(row_ptr, stb, wbuf, 0, emb, embB);
    k_edge_d<bf16, float><<<R_NUM / 4, 256, 0, stream>>>(row_ptr, stb, wbuf, 1, embB, emb);
  }
}

// Round 4
// 296.879 us; speedup vs baseline: 1.0095x; 1.0095x over previous
//
#include <hip/hip_runtime.h>
#include <hip/hip_bf16.h>

typedef __hip_bfloat16 bf16;

#define R_NUM 40000
#define E_NUM 500000
#define HIST_BLOCKS 1954  // ceil(E/256)
#define XFA_BLOCKS 1250   // R/32 (32-row tiles, 8 rows/wave)

// ---------------- new-path ws layout (bytes) ----------------
#define N_CNTS 0
#define N_ROWP 160000
#define N_STB 320000          // E*4 + 256 pad, ends 2,320,256
#define N_XMP0 2320384
#define N_HR0 12560384
#define N_XMP1 33040384
#define N_HR1 43280384
#define NEED2 63760384ull

// ---------------- legacy (PlanD fallback) ws layout ----------------
#define W_P1W 0
#define W_P1B 4096
#define W_APW 4160
#define W_APB 20544
#define W_ABIN 20672
#define W_AVEC 20832
#define W_AW 20960
#define W_AB 29152
#define W_RW 29280
#define W_RB 37472
#define W_END 37600
#define WCONV_BLOCKS 147

#define O_FLAG 0
#define O_WBUF 256
#define O_ROWP 150784
#define O_CNTS 310784
#define O_TMP 470784
#define O_PART 634624
#define O_STB 635136
#define O_BIG 2635392

static __device__ __forceinline__ float b2f(bf16 x) { return __bfloat162float(x); }
static __device__ __forceinline__ float ldv(const float* p, size_t i) { return p[i]; }
static __device__ __forceinline__ float ldv(const bf16* p, size_t i) { return __bfloat162float(p[i]); }
static __device__ __forceinline__ void stv(float* p, size_t i, float v) { p[i] = v; }
static __device__ __forceinline__ void stv(bf16* p, size_t i, float v) { p[i] = __float2bfloat16(v); }

// round-to-nearest-even f32 -> bf16 bits
static __device__ __forceinline__ unsigned int f2bb(float x) {
  union { float f; unsigned int u; } v;
  v.f = x;
  unsigned int r = v.u + 0x7FFFu + ((v.u >> 16) & 1u);
  return r >> 16;
}
static __device__ __forceinline__ unsigned int packxm(float xt, float mt) {
  return f2bb(xt) | (f2bb(mt) << 16);
}

static __device__ __forceinline__ void load_edge(const unsigned int* __restrict__ w, int e,
                                                 int i64, int& h, int& t, int& b) {
  if (i64) {
    h = (int)w[6 * e + 0];
    t = (int)w[6 * e + 2];
    b = (int)w[6 * e + 4];
  } else {
    h = (int)w[3 * e + 0];
    t = (int)w[3 * e + 1];
    b = (int)w[3 * e + 2];
  }
}

// ---------------- detect + zero-init (1 launch) ----------------

__global__ void k_detect_init(const unsigned int* __restrict__ trip_w,
                              const unsigned short* __restrict__ emb_w, int* __restrict__ flag,
                              int* __restrict__ counts, int* __restrict__ stb) {
  int tid = threadIdx.x;
  if (blockIdx.x == 0) {
    if (tid < 64) {
      int lane = tid;
      unsigned int acc = 0;
      for (int i = lane; i < 1024; i += 64) acc |= trip_w[2 * i + 1];
      int votes = 0;
      for (int i = lane; i < 2048; i += 64) {
        unsigned short u = emb_w[2 * i];
        int ex = (u >> 7) & 0xFF;
        if (ex >= 90 && ex <= 130) votes++;
      }
      for (int off = 1; off < 64; off <<= 1) {
        acc |= __shfl_xor(acc, off);
        votes += __shfl_xor(votes, off);
      }
      if (lane == 0) {
        flag[0] = (acc == 0) ? 1 : 0;
        flag[1] = (votes < 1024) ? 1 : 0;
      }
    }
    return;
  }
  int g = (blockIdx.x - 1) * 256 + tid;
  for (int i = g; i < R_NUM; i += 159 * 256) counts[i] = 0;
  if (blockIdx.x == 1 && tid < 64) stb[E_NUM + tid] = 0;
}

// ---------------- shared transform core: 4 fused streams, N rows/wave ----------------

template <typename WT, int N>
static __device__ __forceinline__ void xf4t(const float (*sA)[64], int base, int j, int l,
                                            const WT* __restrict__ apw, const WT* __restrict__ apb,
                                            const WT* __restrict__ aw, const WT* __restrict__ ab,
                                            const WT* __restrict__ rw, const WT* __restrict__ rb,
                                            int r0, unsigned int* __restrict__ XMp,
                                            float2* __restrict__ HR) {
  const WT* pwt = apw + l * 8192;
  const WT* pwb = pwt + 4096;
  const WT* awl = aw + l * 4096;
  const WT* rwl = rw + l * 4096;
  float axt[N] = {};
  float amt[N] = {};
  float axh[N] = {};
  float ars[N] = {};
  for (int i4 = 0; i4 < 64; i4 += 4) {
    float4 ev[N];
#pragma unroll
    for (int n = 0; n < N; n++) ev[n] = *(const float4*)&sA[base + n][i4];
#pragma unroll
    for (int di = 0; di < 4; di++) {
      int i = i4 + di;
      float wt = ldv(pwb, (size_t)i * 64 + j);
      float wm = ldv(awl, (size_t)i * 64 + j);
      float wh = ldv(pwt, (size_t)i * 64 + j);
      float wr = ldv(rwl, (size_t)i * 64 + j);
#pragma unroll
      for (int n = 0; n < N; n++) {
        float e = ((const float*)&ev[n])[di];
        axt[n] = fmaf(e, wt, axt[n]);
        amt[n] = fmaf(e, wm, amt[n]);
        axh[n] = fmaf(e, wh, axh[n]);
        ars[n] = fmaf(e, wr, ars[n]);
      }
    }
  }
  float abj = ldv(ab, (size_t)l * 64 + j);
  float pbj = ldv(apb, (size_t)l * 64 + j);
  float rbj = ldv(rb, (size_t)l * 64 + j);
#pragma unroll
  for (int n = 0; n < N; n++) {
    XMp[(size_t)(r0 + n) * 64 + j] = packxm(axt[n], amt[n] + abj);
    HR[(size_t)(r0 + n) * 64 + j] = make_float2(axh[n] + pbj, fmaxf(ars[n] + rbj, 0.f));
  }
}

// ---------------- kA: emb0/layer-0 transform tiles (first) + hist blocks (1 launch) --------
// Transform tile = 32 rows, 8 rows/wave (R2's no-spill config, VGPR~100 under bound-4 cap).
// hist writes counts; transform blocks read inputs, write XMp0/HR0 — no cross-block deps.
// The layer-0 emb store is DEAD (edge-l0 consumes XMp/HR only) and is eliminated.

template <typename T>
static __device__ __forceinline__ void kA_xform(const T* __restrict__ A, const T* __restrict__ p1w,
                                                const T* __restrict__ p1b,
                                                const T* __restrict__ apw,
                                                const T* __restrict__ apb, const T* __restrict__ aw,
                                                const T* __restrict__ ab, const T* __restrict__ rw,
                                                const T* __restrict__ rb, int u,
                                                unsigned int* __restrict__ XMp0,
                                                float2* __restrict__ HR0, float (*sA)[64]) {
  int tid = threadIdx.x;
  int j = tid & 63;
  int g = tid >> 6;
  int base = g * 8;
  for (int k = tid; k < 2048; k += 256) {
    int rr = k >> 6, cc = k & 63;
    sA[rr][cc] = ldv(A, (size_t)(u * 32 + rr) * 64 + cc);
  }
  __syncthreads();
  float a[8] = {0.f, 0.f, 0.f, 0.f, 0.f, 0.f, 0.f, 0.f};
  for (int i4 = 0; i4 < 64; i4 += 4) {
    float4 ev[8];
#pragma unroll
    for (int n = 0; n < 8; n++) ev[n] = *(const float4*)&sA[base + n][i4];
#pragma unroll
    for (int di = 0; di < 4; di++) {
      float wv = ldv(p1w, (size_t)(i4 + di) * 64 + j);
#pragma unroll
      for (int n = 0; n < 8; n++) a[n] = fmaf(((const float*)&ev[n])[di], wv, a[n]);
    }
  }
  float bj = ldv(p1b, j);
#pragma unroll
  for (int n = 0; n < 8; n++) a[n] = fmaxf(a[n] + bj, 0.f);
  __syncthreads();
#pragma unroll
  for (int n = 0; n < 8; n++) sA[base + n][j] = a[n];
  __syncthreads();
  xf4t<T, 8>((const float(*)[64])sA, base, j, 0, apw, apb, aw, ab, rw, rb, u * 32 + base, XMp0,
             HR0);
}

__global__ void __launch_bounds__(256, 4) kA(const unsigned int* __restrict__ trip_w,
                                             const int* __restrict__ flag,
                                             const void* __restrict__ A, const void* p1w,
                                             const void* p1b, const void* apw, const void* apb,
                                             const void* aw, const void* ab, const void* rw,
                                             const void* rb, int* __restrict__ counts,
                                             unsigned int* __restrict__ XMp0,
                                             float2* __restrict__ HR0) {
  if (blockIdx.x >= XFA_BLOCKS) {
    int e = (blockIdx.x - XFA_BLOCKS) * 256 + threadIdx.x;
    if (e < E_NUM) {
      int h = flag[0] ? (int)trip_w[6 * e] : (int)trip_w[3 * e];
      atomicAdd(&counts[h], 1);
    }
    return;
  }
  __shared__ float sA[32][64];
  int u = blockIdx.x;
  if (flag[1])
    kA_xform<float>((const float*)A, (const float*)p1w, (const float*)p1b, (const float*)apw,
                    (const float*)apb, (const float*)aw, (const float*)ab, (const float*)rw,
                    (const float*)rb, u, XMp0, HR0, sA);
  else
    kA_xform<bf16>((const bf16*)A, (const bf16*)p1w, (const bf16*)p1b, (const bf16*)apw,
                   (const bf16*)apb, (const bf16*)aw, (const bf16*)ab, (const bf16*)rw,
                   (const bf16*)rb, u, XMp0, HR0, sA);
}

// ---------------- single-block scan: counts -> exclusive row_ptr (1 launch) ----------------

__global__ void __launch_bounds__(1024) k_scan1(const int* __restrict__ counts,
                                                int* __restrict__ row_ptr) {
  __shared__ int sp[1024];
  int tid = threadIdx.x;
  int base = tid * 40;  // 1000 threads x 40 = 40000
  int local[40];
  int s = 0;
  if (base < R_NUM) {
#pragma unroll
    for (int k = 0; k < 40; k++) {
      int v = counts[base + k];
      local[k] = s;
      s += v;
    }
  }
  sp[tid] = s;
  __syncthreads();
  for (int off = 1; off < 1024; off <<= 1) {
    int t = (tid >= off) ? sp[tid - off] : 0;
    __syncthreads();
    sp[tid] += t;
    __syncthreads();
  }
  int pre = (tid == 0) ? 0 : sp[tid - 1];
  if (base < R_NUM) {
#pragma unroll
    for (int k = 0; k < 40; k++) row_ptr[base + k] = pre + local[k];
  }
}

// scatter bumps row_ptr: afterwards row_ptr[r] == end(r); beg(r) = r ? row_ptr[r-1] : 0
__global__ void k_scatter(const unsigned int* __restrict__ trip_w, const int* __restrict__ flag,
                          int* __restrict__ row_ptr, int* __restrict__ stb) {
  int e = blockIdx.x * 256 + threadIdx.x;
  if (e >= E_NUM) return;
  int h, t, b;
  load_edge(trip_w, e, flag[0], h, t, b);
  int pos = atomicAdd(&row_ptr[h], 1);
  stb[pos] = (t & 0xFFFF) | (b << 16);
}

// ---------------- kB2: edge-l0 aggregation + PER-ROW layer-1 transform (1 launch) ----------
// 10000 blocks, 1 row/wave: edge phase keeps full gather parallelism; the l1 transform is
// row-local (XMp1[r] depends only on new emb row r, held across the wave's 64 lanes), done
// in-wave via __shfl broadcast — no sync, no emb round-trip, no extra kernel.

template <typename T>
static __device__ __forceinline__ void kB2_body(const int* __restrict__ row_ptr,
                                                const int* __restrict__ stb,
                                                const unsigned int* __restrict__ XMp0,
                                                const float2* __restrict__ HR0,
                                                const T* __restrict__ apw,
                                                const T* __restrict__ apb,
                                                const T* __restrict__ abin,
                                                const T* __restrict__ avec,
                                                const T* __restrict__ aw, const T* __restrict__ ab,
                                                const T* __restrict__ rw, const T* __restrict__ rb,
                                                unsigned int* __restrict__ XMp1,
                                                float2* __restrict__ HR1, float* sab) {
  int tid = threadIdx.x;
  int lane = tid & 63;
  int w = tid >> 6;
  int hh = lane >> 3;
  if (tid < 80) {
    float a = ldv(abin, tid);  // l=0
    sab[tid] = (a > 0.f) ? a : 0.2f * a;
  }
  __syncthreads();
  float av = ldv(avec, lane);  // l=0

  int r = blockIdx.x * 4 + w;
  float2 hr = HR0[(size_t)r * 64 + lane];
  int beg = (r == 0) ? 0 : row_ptr[r - 1];
  int end = row_ptr[r];
  beg = __builtin_amdgcn_readfirstlane(beg);
  end = __builtin_amdgcn_readfirstlane(end);

  float xh = hr.x;
  float num = 0.f, den = 0.f;
  for (int jj = beg; jj < end; jj += 16) {
    int pk[16];
    unsigned int xp[16];
#pragma unroll
    for (int k = 0; k < 16; k++) pk[k] = stb[jj + k];  // uniform scalar loads
#pragma unroll
    for (int k = 0; k < 16; k++)
      xp[k] = XMp0[(size_t)(pk[k] & 0xFFFF) * 64 + lane];  // 16 gathers in flight
#pragma unroll
    for (int k = 0; k < 16; k++) {
      float xt = __uint_as_float(xp[k] << 16);
      float mt = __uint_as_float(xp[k] & 0xFFFF0000u);
      float z = xh + xt;
      z = (z > 0.f) ? z : 0.2f * z;
      float v = z * av;
      v += __shfl_xor(v, 1);
      v += __shfl_xor(v, 2);
      v += __shfl_xor(v, 4);
      float e = __expf(v + sab[(pk[k] >> 16) * 8 + hh]);
      e = (jj + k < end) ? e : 0.f;
      den += e;
      num = fmaf(mt, e, num);
    }
  }
  float val = fmaxf(num / (den + 1e-16f), 0.f) + hr.y;  // new emb row r, dim=lane

  // ---- layer-1 transform for row r (in-wave, shfl broadcast), 4 fused streams ----
  const T* pwt = apw + 8192;   // l=1 top proj
  const T* pwb = pwt + 4096;   // l=1 bottom proj
  const T* awl = aw + 4096;    // l=1 aggr
  const T* rwl = rw + 4096;    // l=1 res
  float axt = 0.f, amt = 0.f, axh = 0.f, ars = 0.f;
#pragma unroll 16
  for (int i = 0; i < 64; i++) {
    float e = __shfl(val, i);
    axt = fmaf(e, ldv(pwb, (size_t)i * 64 + lane), axt);
    amt = fmaf(e, ldv(awl, (size_t)i * 64 + lane), amt);
    axh = fmaf(e, ldv(pwt, (size_t)i * 64 + lane), axh);
    ars = fmaf(e, ldv(rwl, (size_t)i * 64 + lane), ars);
  }
  XMp1[(size_t)r * 64 + lane] = packxm(axt, amt + ldv(ab, 64 + lane));
  HR1[(size_t)r * 64 + lane] =
      make_float2(axh + ldv(apb, 64 + lane), fmaxf(ars + ldv(rb, 64 + lane), 0.f));
}

__global__ void __launch_bounds__(256, 4) kB2(const int* __restrict__ row_ptr,
                                              const int* __restrict__ stb,
                                              const int* __restrict__ flag,
                                              const unsigned int* __restrict__ XMp0,
                                              const float2* __restrict__ HR0, const void* apw,
                                              const void* apb, const void* abin, const void* avec,
                                              const void* aw, const void* ab, const void* rw,
                                              const void* rb, unsigned int* __restrict__ XMp1,
                                              float2* __restrict__ HR1) {
  __shared__ float sab[80];
  if (flag[1])
    kB2_body<float>(row_ptr, stb, XMp0, HR0, (const float*)apw, (const float*)apb,
                    (const float*)abin, (const float*)avec, (const float*)aw, (const float*)ab,
                    (const float*)rw, (const float*)rb, XMp1, HR1, sab);
  else
    kB2_body<bf16>(row_ptr, stb, XMp0, HR0, (const bf16*)apw, (const bf16*)apb, (const bf16*)abin,
                   (const bf16*)avec, (const bf16*)aw, (const bf16*)ab, (const bf16*)rw,
                   (const bf16*)rb, XMp1, HR1, sab);
}

// ---------------- kC: edge-l1 aggregation -> final output (1 launch) ----------------

template <typename T>
static __device__ __forceinline__ void kC_body(const int* __restrict__ row_ptr,
                                               const int* __restrict__ stb,
                                               const unsigned int* __restrict__ XMp1,
                                               const float2* __restrict__ HR1,
                                               const T* __restrict__ abin,
                                               const T* __restrict__ avec,
                                               float* __restrict__ out, float* sab) {
  int tid = threadIdx.x;
  int lane = tid & 63;
  int w = tid >> 6;
  int hh = lane >> 3;
  if (tid < 80) {
    float a = ldv(abin, 80 + tid);  // l=1
    sab[tid] = (a > 0.f) ? a : 0.2f * a;
  }
  __syncthreads();
  float av = ldv(avec, 64 + lane);  // l=1

  int r = blockIdx.x * 4 + w;
  float2 hr = HR1[(size_t)r * 64 + lane];
  int beg = (r == 0) ? 0 : row_ptr[r - 1];
  int end = row_ptr[r];
  beg = __builtin_amdgcn_readfirstlane(beg);
  end = __builtin_amdgcn_readfirstlane(end);

  float xh = hr.x;
  float num = 0.f, den = 0.f;
  for (int j = beg; j < end; j += 16) {
    int pk[16];
    unsigned int xp[16];
#pragma unroll
    for (int k = 0; k < 16; k++) pk[k] = stb[j + k];
#pragma unroll
    for (int k = 0; k < 16; k++) xp[k] = XMp1[(size_t)(pk[k] & 0xFFFF) * 64 + lane];
#pragma unroll
    for (int k = 0; k < 16; k++) {
      float xt = __uint_as_float(xp[k] << 16);
      float mt = __uint_as_float(xp[k] & 0xFFFF0000u);
      float z = xh + xt;
      z = (z > 0.f) ? z : 0.2f * z;
      float v = z * av;
      v += __shfl_xor(v, 1);
      v += __shfl_xor(v, 2);
      v += __shfl_xor(v, 4);
      float e = __expf(v + sab[(pk[k] >> 16) * 8 + hh]);
      e = (j + k < end) ? e : 0.f;
      den += e;
      num = fmaf(mt, e, num);
    }
  }
  out[(size_t)r * 64 + lane] = fmaxf(num / (den + 1e-16f), 0.f) + hr.y;
}

__global__ void __launch_bounds__(256, 4) kC(const int* __restrict__ row_ptr,
                                             const int* __restrict__ stb,
                                             const int* __restrict__ flag,
                                             const unsigned int* __restrict__ XMp1,
                                             const float2* __restrict__ HR1, const void* abin,
                                             const void* avec, float* __restrict__ out) {
  __shared__ float sab[80];
  if (flag[1])
    kC_body<float>(row_ptr, stb, XMp1, HR1, (const float*)abin, (const float*)avec, out, sab);
  else
    kC_body<bf16>(row_ptr, stb, XMp1, HR1, (const bf16*)abin, (const bf16*)avec, out, sab);
}

// ==================== legacy fallback (tiny ws): wconv + PlanD ====================

__global__ void k_hist_wconv(const unsigned int* __restrict__ trip_w, const int* __restrict__ flag,
                             int* __restrict__ counts, const void* p1w, const void* p1b,
                             const void* apw, const void* apb, const void* abin, const void* avec,
                             const void* aw, const void* ab, const void* rw, const void* rb,
                             float* __restrict__ wbuf) {
  if (blockIdx.x < WCONV_BLOCKS) {
    int i = blockIdx.x * 256 + threadIdx.x;
    if (i >= W_END) return;
    const void* src;
    int off;
    if (i < W_P1B) { src = p1w; off = i - W_P1W; }
    else if (i < W_APW) { src = p1b; off = i - W_P1B; }
    else if (i < W_APB) { src = apw; off = i - W_APW; }
    else if (i < W_ABIN) { src = apb; off = i - W_APB; }
    else if (i < W_AVEC) { src = abin; off = i - W_ABIN; }
    else if (i < W_AW) { src = avec; off = i - W_AVEC; }
    else if (i < W_AB) { src = aw; off = i - W_AW; }
    else if (i < W_RW) { src = ab; off = i - W_AB; }
    else if (i < W_RB) { src = rw; off = i - W_RW; }
    else { src = rb; off = i - W_RB; }
    wbuf[i] = flag[1] ? ((const float*)src)[off] : b2f(((const bf16*)src)[off]);
    return;
  }
  int e = (blockIdx.x - WCONV_BLOCKS) * 256 + threadIdx.x;
  if (e >= E_NUM) return;
  int h, t, b;
  load_edge(trip_w, e, flag[0], h, t, b);
  atomicAdd(&counts[h], 1);
}

__global__ void k_emb0(const void* __restrict__ A, const int* __restrict__ flag,
                       const float* __restrict__ wbuf, float* __restrict__ emb) {
  int j = threadIdx.x & 63;
  int g = threadIdx.x >> 6;
  int r0 = blockIdx.x * 16 + g * 4;
  int f32 = flag[1];
  __shared__ float sA[16][64];
  for (int k = threadIdx.x; k < 1024; k += 256) {
    int rr = k >> 6, cc = k & 63;
    size_t idx = (size_t)(blockIdx.x * 16 + rr) * 64 + cc;
    sA[rr][cc] = f32 ? ((const float*)A)[idx] : b2f(((const bf16*)A)[idx]);
  }
  __syncthreads();
  const float* W = wbuf + W_P1W;
  float a[4] = {0.f, 0.f, 0.f, 0.f};
  int base = g * 4;
  for (int i = 0; i < 64; i++) {
    float w = W[i * 64 + j];
#pragma unroll
    for (int n = 0; n < 4; n++) a[n] = fmaf(sA[base + n][i], w, a[n]);
  }
  float bj = wbuf[W_P1B + j];
#pragma unroll
  for (int n = 0; n < 4; n++)
    emb[(size_t)(r0 + n) * 64 + j] = fmaxf(a[n] + bj, 0.f);
}

static __device__ __forceinline__ float dotcol(const float* __restrict__ Wm, float val, int lane) {
  float acc = 0.f;
  for (int i = 0; i < 64; i++) acc = fmaf(__shfl(val, i), Wm[i * 64 + lane], acc);
  return acc;
}

template <typename TIN, typename TOUT>
__global__ void k_edge_d(const int* __restrict__ row_ptr, const int* __restrict__ stb,
                         const float* __restrict__ wbuf, int l, const TIN* __restrict__ emb_in,
                         TOUT* __restrict__ emb_out) {
  __shared__ float sab[80];
  int tid = threadIdx.x;
  int lane = tid & 63;
  int w = tid >> 6;
  int r = blockIdx.x * 4 + w;
  int hh = lane >> 3;
  if (tid < 80) {
    float a = wbuf[W_ABIN + l * 80 + tid];
    sab[tid] = (a > 0.f) ? a : 0.2f * a;
  }
  __syncthreads();
  const float* pwt = wbuf + W_APW + l * 8192;
  const float* pwb = pwt + 4096;
  const float* aw = wbuf + W_AW + l * 4096;
  const float* rw = wbuf + W_RW + l * 4096;

  float ev = ldv(emb_in, (size_t)r * 64 + lane);
  float xh = wbuf[W_APB + l * 64 + lane];
  float res = wbuf[W_RB + l * 64 + lane];
  for (int i = 0; i < 64; i++) {
    float e = __shfl(ev, i);
    xh = fmaf(e, pwt[i * 64 + lane], xh);
    res = fmaf(e, rw[i * 64 + lane], res);
  }
  res = fmaxf(res, 0.f);
  float av = wbuf[W_AVEC + l * 64 + lane];
  float abl = wbuf[W_AB + l * 64 + lane];

  int beg = (r == 0) ? 0 : row_ptr[r - 1];
  int end = row_ptr[r];
  float num = 0.f, den = 0.f;
  for (int j = beg; j < end; j++) {
    int p = stb[j];
    int t = p & 0xFFFF;
    float tv = ldv(emb_in, (size_t)t * 64 + lane);
    float z = xh + dotcol(pwb, tv, lane);
    z = (z > 0.f) ? z : 0.2f * z;
    float v = z * av;
    v += __shfl_xor(v, 1);
    v += __shfl_xor(v, 2);
    v += __shfl_xor(v, 4);
    float e = __expf(v + sab[(p >> 16) * 8 + hh]);
    den += e;
    float mt = dotcol(aw, tv, lane) + abl;
    num = fmaf(mt, e, num);
  }
  stv(emb_out, (size_t)r * 64 + lane, fmaxf(num / (den + 1e-16f), 0.f) + res);
}

// ---------------- launch ----------------

extern "C" void kernel_launch(void* const* d_in, const int* in_sizes, int n_in,
                              void* d_out, int out_size, void* d_ws, size_t ws_size,
                              hipStream_t stream) {
  const unsigned int* trip_w = (const unsigned int*)d_in[0];
  const void* rel_emb = d_in[1];
  float* emb = (float*)d_out;
  char* ws = (char*)d_ws;

  if (ws_size >= NEED2) {
    int* counts = (int*)(ws + N_CNTS);
    int* row_ptr = (int*)(ws + N_ROWP);
    int* stb = (int*)(ws + N_STB);
    unsigned int* XMp0 = (unsigned int*)(ws + N_XMP0);
    float2* HR0 = (float2*)(ws + N_HR0);
    unsigned int* XMp1 = (unsigned int*)(ws + N_XMP1);
    float2* HR1 = (float2*)(ws + N_HR1);
    // flag lives in the gap after stb pad (aligned, unused bytes)
    int* flag = (int*)(ws + N_STB + (E_NUM + 64) * 4);

    k_detect_init<<<160, 256, 0, stream>>>(trip_w, (const unsigned short*)rel_emb, flag, counts,
                                           stb);
    kA<<<XFA_BLOCKS + HIST_BLOCKS, 256, 0, stream>>>(trip_w, flag, rel_emb, d_in[2], d_in[3],
                                                     d_in[4], d_in[5], d_in[8], d_in[9], d_in[10],
                                                     d_in[11], counts, XMp0, HR0);
    k_scan1<<<1, 1024, 0, stream>>>(counts, row_ptr);
    k_scatter<<<HIST_BLOCKS, 256, 0, stream>>>(trip_w, flag, row_ptr, stb);
    kB2<<<R_NUM / 4, 256, 0, stream>>>(row_ptr, stb, flag, XMp0, HR0, d_in[4], d_in[5], d_in[6],
                                       d_in[7], d_in[8], d_in[9], d_in[10], d_in[11], XMp1, HR1);
    kC<<<R_NUM / 4, 256, 0, stream>>>(row_ptr, stb, flag, XMp1, HR1, d_in[6], d_in[7], emb);
    return;
  }

  // ---- tiny-ws fallback: legacy wconv + PlanD per-edge recompute ----
  {
    int* flag = (int*)(ws + O_FLAG);
    float* wbuf = (float*)(ws + O_WBUF);
    int* row_ptr = (int*)(ws + O_ROWP);
    int* counts = (int*)(ws + O_CNTS);
    int* stb = (int*)(ws + O_STB);
    char* big = ws + O_BIG;

    k_detect_init<<<160, 256, 0, stream>>>(trip_w, (const unsigned short*)rel_emb, flag, counts,
                                           stb);
    k_hist_wconv<<<WCONV_BLOCKS + HIST_BLOCKS, 256, 0, stream>>>(
        trip_w, flag, counts, d_in[2], d_in[3], d_in[4], d_in[5], d_in[6], d_in[7], d_in[8],
        d_in[9], d_in[10], d_in[11], wbuf);
    k_scan1<<<1, 1024, 0, stream>>>(counts, row_ptr);
    k_scatter<<<HIST_BLOCKS, 256, 0, stream>>>(trip_w, flag, row_ptr, stb);
    k_emb0<<<R_NUM / 16, 256, 0, stream>>>(rel_emb, flag, wbuf, emb);
    bf16* embB = (bf16*)big;
    k_edge_d<float, bf16><<<R_NUM / 4, 256, 0, stream>>>(row_ptr, stb, wbuf, 0, emb, embB);
    k_edge_d<bf16, float><<<R_NUM / 4, 256, 0, stream>>>(row_ptr, stb, wbuf, 1, embB, emb);
  }
}

// Round 5
// 258.773 us; speedup vs baseline: 1.1582x; 1.1473x over previous
//
#include <hip/hip_runtime.h>
#include <hip/hip_bf16.h>

typedef __hip_bfloat16 bf16;

#define R_NUM 40000
#define E_NUM 500000
#define HIST_BLOCKS 1954  // ceil(E/256)
#define XFA_BLOCKS 1250   // R/32 (32-row tiles, 8 rows/wave)

// ---------------- new-path ws layout (bytes) ----------------
#define N_CNTS 0
#define N_ROWP 160000
#define N_STB 320000          // E*4 + 256 pad, ends 2,320,256
#define N_XMP0 2320384
#define N_HR0 12560384
#define N_XMP1 33040384
#define N_HR1 43280384
#define NEED2 63760384ull

// ---------------- legacy (PlanD fallback) ws layout ----------------
#define W_P1W 0
#define W_P1B 4096
#define W_APW 4160
#define W_APB 20544
#define W_ABIN 20672
#define W_AVEC 20832
#define W_AW 20960
#define W_AB 29152
#define W_RW 29280
#define W_RB 37472
#define W_END 37600
#define WCONV_BLOCKS 147

#define O_FLAG 0
#define O_WBUF 256
#define O_ROWP 150784
#define O_CNTS 310784
#define O_TMP 470784
#define O_PART 634624
#define O_STB 635136
#define O_BIG 2635392

static __device__ __forceinline__ float b2f(bf16 x) { return __bfloat162float(x); }
static __device__ __forceinline__ float ldv(const float* p, size_t i) { return p[i]; }
static __device__ __forceinline__ float ldv(const bf16* p, size_t i) { return __bfloat162float(p[i]); }
static __device__ __forceinline__ void stv(float* p, size_t i, float v) { p[i] = v; }
static __device__ __forceinline__ void stv(bf16* p, size_t i, float v) { p[i] = __float2bfloat16(v); }

// round-to-nearest-even f32 -> bf16 bits
static __device__ __forceinline__ unsigned int f2bb(float x) {
  union { float f; unsigned int u; } v;
  v.f = x;
  unsigned int r = v.u + 0x7FFFu + ((v.u >> 16) & 1u);
  return r >> 16;
}
static __device__ __forceinline__ unsigned int packxm(float xt, float mt) {
  return f2bb(xt) | (f2bb(mt) << 16);
}

static __device__ __forceinline__ void load_edge(const unsigned int* __restrict__ w, int e,
                                                 int i64, int& h, int& t, int& b) {
  if (i64) {
    h = (int)w[6 * e + 0];
    t = (int)w[6 * e + 2];
    b = (int)w[6 * e + 4];
  } else {
    h = (int)w[3 * e + 0];
    t = (int)w[3 * e + 1];
    b = (int)w[3 * e + 2];
  }
}

// ---------------- detect + zero-init (1 launch) ----------------

__global__ void k_detect_init(const unsigned int* __restrict__ trip_w,
                              const unsigned short* __restrict__ emb_w, int* __restrict__ flag,
                              int* __restrict__ counts, int* __restrict__ stb) {
  int tid = threadIdx.x;
  if (blockIdx.x == 0) {
    if (tid < 64) {
      int lane = tid;
      unsigned int acc = 0;
      for (int i = lane; i < 1024; i += 64) acc |= trip_w[2 * i + 1];
      int votes = 0;
      for (int i = lane; i < 2048; i += 64) {
        unsigned short u = emb_w[2 * i];
        int ex = (u >> 7) & 0xFF;
        if (ex >= 90 && ex <= 130) votes++;
      }
      for (int off = 1; off < 64; off <<= 1) {
        acc |= __shfl_xor(acc, off);
        votes += __shfl_xor(votes, off);
      }
      if (lane == 0) {
        flag[0] = (acc == 0) ? 1 : 0;
        flag[1] = (votes < 1024) ? 1 : 0;
      }
    }
    return;
  }
  int g = (blockIdx.x - 1) * 256 + tid;
  for (int i = g; i < R_NUM; i += 159 * 256) counts[i] = 0;
  if (blockIdx.x == 1 && tid < 64) stb[E_NUM + tid] = 0;
}

// ---------------- shared transform core: 4 fused streams, N rows/wave ----------------

template <typename WT, int N>
static __device__ __forceinline__ void xf4t(const float (*sA)[64], int base, int j, int l,
                                            const WT* __restrict__ apw, const WT* __restrict__ apb,
                                            const WT* __restrict__ aw, const WT* __restrict__ ab,
                                            const WT* __restrict__ rw, const WT* __restrict__ rb,
                                            int r0, unsigned int* __restrict__ XMp,
                                            float2* __restrict__ HR) {
  const WT* pwt = apw + l * 8192;
  const WT* pwb = pwt + 4096;
  const WT* awl = aw + l * 4096;
  const WT* rwl = rw + l * 4096;
  float axt[N] = {};
  float amt[N] = {};
  float axh[N] = {};
  float ars[N] = {};
  for (int i4 = 0; i4 < 64; i4 += 4) {
    float4 ev[N];
#pragma unroll
    for (int n = 0; n < N; n++) ev[n] = *(const float4*)&sA[base + n][i4];
#pragma unroll
    for (int di = 0; di < 4; di++) {
      int i = i4 + di;
      float wt = ldv(pwb, (size_t)i * 64 + j);
      float wm = ldv(awl, (size_t)i * 64 + j);
      float wh = ldv(pwt, (size_t)i * 64 + j);
      float wr = ldv(rwl, (size_t)i * 64 + j);
#pragma unroll
      for (int n = 0; n < N; n++) {
        float e = ((const float*)&ev[n])[di];
        axt[n] = fmaf(e, wt, axt[n]);
        amt[n] = fmaf(e, wm, amt[n]);
        axh[n] = fmaf(e, wh, axh[n]);
        ars[n] = fmaf(e, wr, ars[n]);
      }
    }
  }
  float abj = ldv(ab, (size_t)l * 64 + j);
  float pbj = ldv(apb, (size_t)l * 64 + j);
  float rbj = ldv(rb, (size_t)l * 64 + j);
#pragma unroll
  for (int n = 0; n < N; n++) {
    XMp[(size_t)(r0 + n) * 64 + j] = packxm(axt[n], amt[n] + abj);
    HR[(size_t)(r0 + n) * 64 + j] = make_float2(axh[n] + pbj, fmaxf(ars[n] + rbj, 0.f));
  }
}

// ---------------- kA: emb0/layer-0 transform tiles (first) + hist blocks (1 launch) --------
// Transform tile = 32 rows, 8 rows/wave. hist writes counts; transform blocks read inputs,
// write XMp0/HR0 — no cross-block deps. The layer-0 emb store is DEAD and is eliminated.

template <typename T>
static __device__ __forceinline__ void kA_xform(const T* __restrict__ A, const T* __restrict__ p1w,
                                                const T* __restrict__ p1b,
                                                const T* __restrict__ apw,
                                                const T* __restrict__ apb, const T* __restrict__ aw,
                                                const T* __restrict__ ab, const T* __restrict__ rw,
                                                const T* __restrict__ rb, int u,
                                                unsigned int* __restrict__ XMp0,
                                                float2* __restrict__ HR0, float (*sA)[64]) {
  int tid = threadIdx.x;
  int j = tid & 63;
  int g = tid >> 6;
  int base = g * 8;
  for (int k = tid; k < 2048; k += 256) {
    int rr = k >> 6, cc = k & 63;
    sA[rr][cc] = ldv(A, (size_t)(u * 32 + rr) * 64 + cc);
  }
  __syncthreads();
  float a[8] = {0.f, 0.f, 0.f, 0.f, 0.f, 0.f, 0.f, 0.f};
  for (int i4 = 0; i4 < 64; i4 += 4) {
    float4 ev[8];
#pragma unroll
    for (int n = 0; n < 8; n++) ev[n] = *(const float4*)&sA[base + n][i4];
#pragma unroll
    for (int di = 0; di < 4; di++) {
      float wv = ldv(p1w, (size_t)(i4 + di) * 64 + j);
#pragma unroll
      for (int n = 0; n < 8; n++) a[n] = fmaf(((const float*)&ev[n])[di], wv, a[n]);
    }
  }
  float bj = ldv(p1b, j);
#pragma unroll
  for (int n = 0; n < 8; n++) a[n] = fmaxf(a[n] + bj, 0.f);
  __syncthreads();
#pragma unroll
  for (int n = 0; n < 8; n++) sA[base + n][j] = a[n];
  __syncthreads();
  xf4t<T, 8>((const float(*)[64])sA, base, j, 0, apw, apb, aw, ab, rw, rb, u * 32 + base, XMp0,
             HR0);
}

__global__ void __launch_bounds__(256, 4) kA(const unsigned int* __restrict__ trip_w,
                                             const int* __restrict__ flag,
                                             const void* __restrict__ A, const void* p1w,
                                             const void* p1b, const void* apw, const void* apb,
                                             const void* aw, const void* ab, const void* rw,
                                             const void* rb, int* __restrict__ counts,
                                             unsigned int* __restrict__ XMp0,
                                             float2* __restrict__ HR0) {
  if (blockIdx.x >= XFA_BLOCKS) {
    int e = (blockIdx.x - XFA_BLOCKS) * 256 + threadIdx.x;
    if (e < E_NUM) {
      int h = flag[0] ? (int)trip_w[6 * e] : (int)trip_w[3 * e];
      atomicAdd(&counts[h], 1);
    }
    return;
  }
  __shared__ float sA[32][64];
  int u = blockIdx.x;
  if (flag[1])
    kA_xform<float>((const float*)A, (const float*)p1w, (const float*)p1b, (const float*)apw,
                    (const float*)apb, (const float*)aw, (const float*)ab, (const float*)rw,
                    (const float*)rb, u, XMp0, HR0, sA);
  else
    kA_xform<bf16>((const bf16*)A, (const bf16*)p1w, (const bf16*)p1b, (const bf16*)apw,
                   (const bf16*)apb, (const bf16*)aw, (const bf16*)ab, (const bf16*)rw,
                   (const bf16*)rb, u, XMp0, HR0, sA);
}

// ---------------- single-block scan: counts -> exclusive row_ptr (1 launch) ----------------

__global__ void __launch_bounds__(1024) k_scan1(const int* __restrict__ counts,
                                                int* __restrict__ row_ptr) {
  __shared__ int sp[1024];
  int tid = threadIdx.x;
  int base = tid * 40;  // 1000 threads x 40 = 40000
  int local[40];
  int s = 0;
  if (base < R_NUM) {
#pragma unroll
    for (int k = 0; k < 40; k++) {
      int v = counts[base + k];
      local[k] = s;
      s += v;
    }
  }
  sp[tid] = s;
  __syncthreads();
  for (int off = 1; off < 1024; off <<= 1) {
    int t = (tid >= off) ? sp[tid - off] : 0;
    __syncthreads();
    sp[tid] += t;
    __syncthreads();
  }
  int pre = (tid == 0) ? 0 : sp[tid - 1];
  if (base < R_NUM) {
#pragma unroll
    for (int k = 0; k < 40; k++) row_ptr[base + k] = pre + local[k];
  }
}

// scatter bumps row_ptr: afterwards row_ptr[r] == end(r); beg(r) = r ? row_ptr[r-1] : 0
__global__ void k_scatter(const unsigned int* __restrict__ trip_w, const int* __restrict__ flag,
                          int* __restrict__ row_ptr, int* __restrict__ stb) {
  int e = blockIdx.x * 256 + threadIdx.x;
  if (e >= E_NUM) return;
  int h, t, b;
  load_edge(trip_w, e, flag[0], h, t, b);
  int pos = atomicAdd(&row_ptr[h], 1);
  stb[pos] = (t & 0xFFFF) | (b << 16);
}

// ---------------- pure edge aggregation body (1 row/wave, window-16, tail-clamped) ---------
// Live set ~45 VGPR (pk[] uniform -> SGPRs) => fits launch_bounds(256,8): 2x resident waves
// vs bound-4. Tail gathers clamped to the row's first target (scalar select: window-boundary
// test is wave-uniform) — kills ~30% wasted HBM fetch from window padding.

template <typename T>
static __device__ __forceinline__ void edge_body(int l, const int* __restrict__ row_ptr,
                                                 const int* __restrict__ stb,
                                                 const unsigned int* __restrict__ XMp,
                                                 const float2* __restrict__ HR,
                                                 const T* __restrict__ abin,
                                                 const T* __restrict__ avec,
                                                 float* __restrict__ out, float* sab) {
  int tid = threadIdx.x;
  int lane = tid & 63;
  int w = tid >> 6;
  int hh = lane >> 3;
  if (tid < 80) {
    float a = ldv(abin, (size_t)l * 80 + tid);
    sab[tid] = (a > 0.f) ? a : 0.2f * a;
  }
  __syncthreads();
  float av = ldv(avec, (size_t)l * 64 + lane);

  int r = blockIdx.x * 4 + w;
  float2 hr = HR[(size_t)r * 64 + lane];
  int beg = (r == 0) ? 0 : row_ptr[r - 1];
  int end = row_ptr[r];
  beg = __builtin_amdgcn_readfirstlane(beg);
  end = __builtin_amdgcn_readfirstlane(end);

  float xh = hr.x;
  float num = 0.f, den = 0.f;
  int t0 = (beg < end) ? (stb[beg] & 0xFFFF) : 0;  // clamp target for padded gathers
  for (int jj = beg; jj < end; jj += 16) {
    int pk[16];
    unsigned int xp[16];
#pragma unroll
    for (int k = 0; k < 16; k++) pk[k] = stb[jj + k];  // uniform scalar loads
#pragma unroll
    for (int k = 0; k < 16; k++) {
      int t = (jj + k < end) ? (pk[k] & 0xFFFF) : t0;  // wave-uniform select
      xp[k] = XMp[(size_t)t * 64 + lane];              // 16 gathers in flight
    }
#pragma unroll
    for (int k = 0; k < 16; k++) {
      float xt = __uint_as_float(xp[k] << 16);
      float mt = __uint_as_float(xp[k] & 0xFFFF0000u);
      float z = xh + xt;
      z = (z > 0.f) ? z : 0.2f * z;
      float v = z * av;
      v += __shfl_xor(v, 1);
      v += __shfl_xor(v, 2);
      v += __shfl_xor(v, 4);
      float e = __expf(v + sab[(pk[k] >> 16) * 8 + hh]);
      e = (jj + k < end) ? e : 0.f;
      den += e;
      num = fmaf(mt, e, num);
    }
  }
  out[(size_t)r * 64 + lane] = fmaxf(num / (den + 1e-16f), 0.f) + hr.y;
}

// kE0: edge layer 0 -> emb (d_out used as scratch)
__global__ void __launch_bounds__(256, 8) kE0(const int* __restrict__ row_ptr,
                                              const int* __restrict__ stb,
                                              const int* __restrict__ flag,
                                              const unsigned int* __restrict__ XMp0,
                                              const float2* __restrict__ HR0, const void* abin,
                                              const void* avec, float* __restrict__ emb) {
  __shared__ float sab[80];
  if (flag[1])
    edge_body<float>(0, row_ptr, stb, XMp0, HR0, (const float*)abin, (const float*)avec, emb, sab);
  else
    edge_body<bf16>(0, row_ptr, stb, XMp0, HR0, (const bf16*)abin, (const bf16*)avec, emb, sab);
}

// kC: edge layer 1 -> final output (overwrites d_out after kX1 consumed it)
__global__ void __launch_bounds__(256, 8) kC(const int* __restrict__ row_ptr,
                                             const int* __restrict__ stb,
                                             const int* __restrict__ flag,
                                             const unsigned int* __restrict__ XMp1,
                                             const float2* __restrict__ HR1, const void* abin,
                                             const void* avec, float* __restrict__ out) {
  __shared__ float sab[80];
  if (flag[1])
    edge_body<float>(1, row_ptr, stb, XMp1, HR1, (const float*)abin, (const float*)avec, out, sab);
  else
    edge_body<bf16>(1, row_ptr, stb, XMp1, HR1, (const bf16*)abin, (const bf16*)avec, out, sab);
}

// ---------------- kX1: layer-1 tile transform: emb -> XMp1/HR1 (1 launch) ----------------

template <typename T>
static __device__ __forceinline__ void kX1_body(const float* __restrict__ emb,
                                                const T* __restrict__ apw,
                                                const T* __restrict__ apb, const T* __restrict__ aw,
                                                const T* __restrict__ ab, const T* __restrict__ rw,
                                                const T* __restrict__ rb, int u,
                                                unsigned int* __restrict__ XMp1,
                                                float2* __restrict__ HR1, float (*sE)[64]) {
  int tid = threadIdx.x;
  int j = tid & 63;
  int g = tid >> 6;
  for (int k = tid; k < 2048; k += 256) {
    int rr = k >> 6, cc = k & 63;
    sE[rr][cc] = emb[(size_t)(u * 32 + rr) * 64 + cc];
  }
  __syncthreads();
  xf4t<T, 8>((const float(*)[64])sE, g * 8, j, 1, apw, apb, aw, ab, rw, rb, u * 32 + g * 8, XMp1,
             HR1);
}

__global__ void __launch_bounds__(256, 4) kX1(const float* __restrict__ emb,
                                              const int* __restrict__ flag, const void* apw,
                                              const void* apb, const void* aw, const void* ab,
                                              const void* rw, const void* rb,
                                              unsigned int* __restrict__ XMp1,
                                              float2* __restrict__ HR1) {
  __shared__ float sE[32][64];
  int u = blockIdx.x;
  if (flag[1])
    kX1_body<float>(emb, (const float*)apw, (const float*)apb, (const float*)aw, (const float*)ab,
                    (const float*)rw, (const float*)rb, u, XMp1, HR1, sE);
  else
    kX1_body<bf16>(emb, (const bf16*)apw, (const bf16*)apb, (const bf16*)aw, (const bf16*)ab,
                   (const bf16*)rw, (const bf16*)rb, u, XMp1, HR1, sE);
}

// ==================== legacy fallback (tiny ws): wconv + PlanD ====================

__global__ void k_hist_wconv(const unsigned int* __restrict__ trip_w, const int* __restrict__ flag,
                             int* __restrict__ counts, const void* p1w, const void* p1b,
                             const void* apw, const void* apb, const void* abin, const void* avec,
                             const void* aw, const void* ab, const void* rw, const void* rb,
                             float* __restrict__ wbuf) {
  if (blockIdx.x < WCONV_BLOCKS) {
    int i = blockIdx.x * 256 + threadIdx.x;
    if (i >= W_END) return;
    const void* src;
    int off;
    if (i < W_P1B) { src = p1w; off = i - W_P1W; }
    else if (i < W_APW) { src = p1b; off = i - W_P1B; }
    else if (i < W_APB) { src = apw; off = i - W_APW; }
    else if (i < W_ABIN) { src = apb; off = i - W_APB; }
    else if (i < W_AVEC) { src = abin; off = i - W_ABIN; }
    else if (i < W_AW) { src = avec; off = i - W_AVEC; }
    else if (i < W_AB) { src = aw; off = i - W_AW; }
    else if (i < W_RW) { src = ab; off = i - W_AB; }
    else if (i < W_RB) { src = rw; off = i - W_RW; }
    else { src = rb; off = i - W_RB; }
    wbuf[i] = flag[1] ? ((const float*)src)[off] : b2f(((const bf16*)src)[off]);
    return;
  }
  int e = (blockIdx.x - WCONV_BLOCKS) * 256 + threadIdx.x;
  if (e >= E_NUM) return;
  int h, t, b;
  load_edge(trip_w, e, flag[0], h, t, b);
  atomicAdd(&counts[h], 1);
}

__global__ void k_emb0(const void* __restrict__ A, const int* __restrict__ flag,
                       const float* __restrict__ wbuf, float* __restrict__ emb) {
  int j = threadIdx.x & 63;
  int g = threadIdx.x >> 6;
  int r0 = blockIdx.x * 16 + g * 4;
  int f32 = flag[1];
  __shared__ float sA[16][64];
  for (int k = threadIdx.x; k < 1024; k += 256) {
    int rr = k >> 6, cc = k & 63;
    size_t idx = (size_t)(blockIdx.x * 16 + rr) * 64 + cc;
    sA[rr][cc] = f32 ? ((const float*)A)[idx] : b2f(((const bf16*)A)[idx]);
  }
  __syncthreads();
  const float* W = wbuf + W_P1W;
  float a[4] = {0.f, 0.f, 0.f, 0.f};
  int base = g * 4;
  for (int i = 0; i < 64; i++) {
    float w = W[i * 64 + j];
#pragma unroll
    for (int n = 0; n < 4; n++) a[n] = fmaf(sA[base + n][i], w, a[n]);
  }
  float bj = wbuf[W_P1B + j];
#pragma unroll
  for (int n = 0; n < 4; n++)
    emb[(size_t)(r0 + n) * 64 + j] = fmaxf(a[n] + bj, 0.f);
}

static __device__ __forceinline__ float dotcol(const float* __restrict__ Wm, float val, int lane) {
  float acc = 0.f;
  for (int i = 0; i < 64; i++) acc = fmaf(__shfl(val, i), Wm[i * 64 + lane], acc);
  return acc;
}

template <typename TIN, typename TOUT>
__global__ void k_edge_d(const int* __restrict__ row_ptr, const int* __restrict__ stb,
                         const float* __restrict__ wbuf, int l, const TIN* __restrict__ emb_in,
                         TOUT* __restrict__ emb_out) {
  __shared__ float sab[80];
  int tid = threadIdx.x;
  int lane = tid & 63;
  int w = tid >> 6;
  int r = blockIdx.x * 4 + w;
  int hh = lane >> 3;
  if (tid < 80) {
    float a = wbuf[W_ABIN + l * 80 + tid];
    sab[tid] = (a > 0.f) ? a : 0.2f * a;
  }
  __syncthreads();
  const float* pwt = wbuf + W_APW + l * 8192;
  const float* pwb = pwt + 4096;
  const float* aw = wbuf + W_AW + l * 4096;
  const float* rw = wbuf + W_RW + l * 4096;

  float ev = ldv(emb_in, (size_t)r * 64 + lane);
  float xh = wbuf[W_APB + l * 64 + lane];
  float res = wbuf[W_RB + l * 64 + lane];
  for (int i = 0; i < 64; i++) {
    float e = __shfl(ev, i);
    xh = fmaf(e, pwt[i * 64 + lane], xh);
    res = fmaf(e, rw[i * 64 + lane], res);
  }
  res = fmaxf(res, 0.f);
  float av = wbuf[W_AVEC + l * 64 + lane];
  float abl = wbuf[W_AB + l * 64 + lane];

  int beg = (r == 0) ? 0 : row_ptr[r - 1];
  int end = row_ptr[r];
  float num = 0.f, den = 0.f;
  for (int j = beg; j < end; j++) {
    int p = stb[j];
    int t = p & 0xFFFF;
    float tv = ldv(emb_in, (size_t)t * 64 + lane);
    float z = xh + dotcol(pwb, tv, lane);
    z = (z > 0.f) ? z : 0.2f * z;
    float v = z * av;
    v += __shfl_xor(v, 1);
    v += __shfl_xor(v, 2);
    v += __shfl_xor(v, 4);
    float e = __expf(v + sab[(p >> 16) * 8 + hh]);
    den += e;
    float mt = dotcol(aw, tv, lane) + abl;
    num = fmaf(mt, e, num);
  }
  stv(emb_out, (size_t)r * 64 + lane, fmaxf(num / (den + 1e-16f), 0.f) + res);
}

// ---------------- launch ----------------

extern "C" void kernel_launch(void* const* d_in, const int* in_sizes, int n_in,
                              void* d_out, int out_size, void* d_ws, size_t ws_size,
                              hipStream_t stream) {
  const unsigned int* trip_w = (const unsigned int*)d_in[0];
  const void* rel_emb = d_in[1];
  float* emb = (float*)d_out;
  char* ws = (char*)d_ws;

  if (ws_size >= NEED2) {
    int* counts = (int*)(ws + N_CNTS);
    int* row_ptr = (int*)(ws + N_ROWP);
    int* stb = (int*)(ws + N_STB);
    unsigned int* XMp0 = (unsigned int*)(ws + N_XMP0);
    float2* HR0 = (float2*)(ws + N_HR0);
    unsigned int* XMp1 = (unsigned int*)(ws + N_XMP1);
    float2* HR1 = (float2*)(ws + N_HR1);
    // flag lives in the gap after stb pad (aligned, unused bytes)
    int* flag = (int*)(ws + N_STB + (E_NUM + 64) * 4);

    k_detect_init<<<160, 256, 0, stream>>>(trip_w, (const unsigned short*)rel_emb, flag, counts,
                                           stb);
    kA<<<XFA_BLOCKS + HIST_BLOCKS, 256, 0, stream>>>(trip_w, flag, rel_emb, d_in[2], d_in[3],
                                                     d_in[4], d_in[5], d_in[8], d_in[9], d_in[10],
                                                     d_in[11], counts, XMp0, HR0);
    k_scan1<<<1, 1024, 0, stream>>>(counts, row_ptr);
    k_scatter<<<HIST_BLOCKS, 256, 0, stream>>>(trip_w, flag, row_ptr, stb);
    kE0<<<R_NUM / 4, 256, 0, stream>>>(row_ptr, stb, flag, XMp0, HR0, d_in[6], d_in[7], emb);
    kX1<<<XFA_BLOCKS, 256, 0, stream>>>(emb, flag, d_in[4], d_in[5], d_in[8], d_in[9], d_in[10],
                                        d_in[11], XMp1, HR1);
    kC<<<R_NUM / 4, 256, 0, stream>>>(row_ptr, stb, flag, XMp1, HR1, d_in[6], d_in[7], emb);
    return;
  }

  // ---- tiny-ws fallback: legacy wconv + PlanD per-edge recompute ----
  {
    int* flag = (int*)(ws + O_FLAG);
    float* wbuf = (float*)(ws + O_WBUF);
    int* row_ptr = (int*)(ws + O_ROWP);
    int* counts = (int*)(ws + O_CNTS);
    int* stb = (int*)(ws + O_STB);
    char* big = ws + O_BIG;

    k_detect_init<<<160, 256, 0, stream>>>(trip_w, (const unsigned short*)rel_emb, flag, counts,
                                           stb);
    k_hist_wconv<<<WCONV_BLOCKS + HIST_BLOCKS, 256, 0, stream>>>(
        trip_w, flag, counts, d_in[2], d_in[3], d_in[4], d_in[5], d_in[6], d_in[7], d_in[8],
        d_in[9], d_in[10], d_in[11], wbuf);
    k_scan1<<<1, 1024, 0, stream>>>(counts, row_ptr);
    k_scatter<<<HIST_BLOCKS, 256, 0, stream>>>(trip_w, flag, row_ptr, stb);
    k_emb0<<<R_NUM / 16, 256, 0, stream>>>(rel_emb, flag, wbuf, emb);
    bf16* embB = (bf16*)big;
    k_edge_d<float, bf16><<<R_NUM / 4, 256, 0, stream>>>(row_ptr, stb, wbuf, 0, emb, embB);
    k_edge_d<bf16, float><<<R_NUM / 4, 256, 0, stream>>>(row_ptr, stb, wbuf, 1, embB, emb);
  }
}